// Round 5
// baseline (847.480 us; speedup 1.0000x reference)
//
#include <hip/hip_runtime.h>
#include <hip/hip_bf16.h>

typedef __attribute__((ext_vector_type(8))) short bf16x8;
typedef __attribute__((ext_vector_type(4))) float floatx4;
typedef __attribute__((ext_vector_type(4))) short short4v;

__device__ inline short f2bf(float f) {
  union { float f; unsigned u; } v; v.f = f;
  unsigned r = v.u + 0x7fffu + ((v.u >> 16) & 1u);  // round-to-nearest-even
  return (short)(r >> 16);
}

__device__ inline void gload_lds16(const short* g, short* l) {
  __builtin_amdgcn_global_load_lds(
      (const __attribute__((address_space(1))) unsigned int*)g,
      (__attribute__((address_space(3))) unsigned int*)l, 16, 0, 0);
}

// ---------------- Kernel 0: fp32 -> bf16 conversion (x and the 3 weight mats)
__global__ __launch_bounds__(256) void cvt_kernel(
    const float* __restrict__ x, const float* __restrict__ wq,
    const float* __restrict__ wk, const float* __restrict__ wv,
    short* __restrict__ Xb, short* __restrict__ Wb) {
  long i4 = (long)(blockIdx.x * 256 + threadIdx.x) * 4;
  const float* src; short* dst; long off;
  if (i4 < 16777216L) {
    src = x; dst = Xb; off = i4;
  } else {
    long j = i4 - 16777216L;
    int mat = (int)(j >> 20);
    src = (mat == 0) ? wq : ((mat == 1) ? wk : wv);
    dst = Wb + ((long)mat << 20);
    off = j & 1048575L;
  }
  float4 v = *(const float4*)(src + off);
  short4v o; o.x = f2bf(v.x); o.y = f2bf(v.y); o.z = f2bf(v.z); o.w = f2bf(v.w);
  *(short4v*)(dst + off) = o;
}

// ---------------- Kernel 1: QKV NT-GEMM (m97 structure), fragment-linear epilogue.
//  Qf/Kf: [b][t16][dc (d>>5)][lane=((d>>3)&3)*16 + (t&15)][j=d&7]
//  Vf   : [b][c16][kc (t>>5)][lane=((t>>3)&3)*16 + (c&15)][j=t&7]
__global__ __launch_bounds__(256) void qkv_gemm(
    const short* __restrict__ Xb, const short* __restrict__ Wb,
    const float* __restrict__ bq, const float* __restrict__ bk,
    const float* __restrict__ bv,
    short* __restrict__ Qf, short* __restrict__ Kf, short* __restrict__ Vf) {
  __shared__ short As[128 * 32];
  __shared__ short Bs[128 * 32];

  const int tid  = threadIdx.x;
  const int wave = tid >> 6, lane = tid & 63;
  const int quad = lane >> 4, l16 = lane & 15;
  const int wm = wave & 1, wn = wave >> 1;

  const int row0 = blockIdx.x * 128;
  const int col0 = blockIdx.y * 128;

  const int srow = wave * 16 + (lane >> 2);
  const int skof = (lane & 3) * 8;
  const short* gA0 = Xb + (size_t)(row0 + srow) * 1024 + skof;
  const short* gA1 = gA0 + (size_t)64 * 1024;
  const short* gB0 = Wb + (size_t)(col0 + srow) * 1024 + skof;
  const short* gB1 = gB0 + (size_t)64 * 1024;
  short* lA0 = As + (wave * 16) * 32 + lane * 8;
  short* lA1 = As + (64 + wave * 16) * 32 + lane * 8;
  short* lB0 = Bs + (wave * 16) * 32 + lane * 8;
  short* lB1 = Bs + (64 + wave * 16) * 32 + lane * 8;

  floatx4 acc[4][4] = {};

  for (int k = 0; k < 1024; k += 32) {
    gload_lds16(gA0 + k, lA0);
    gload_lds16(gA1 + k, lA1);
    gload_lds16(gB0 + k, lB0);
    gload_lds16(gB1 + k, lB1);
    __syncthreads();

    bf16x8 af[4], bfr[4];
#pragma unroll
    for (int mt = 0; mt < 4; mt++)
      af[mt] = *(const bf16x8*)(As + (wm * 64 + mt * 16 + l16) * 32 + quad * 8);
#pragma unroll
    for (int nb = 0; nb < 4; nb++)
      bfr[nb] = *(const bf16x8*)(Bs + (wn * 64 + nb * 16 + l16) * 32 + quad * 8);
#pragma unroll
    for (int mt = 0; mt < 4; mt++)
#pragma unroll
      for (int nb = 0; nb < 4; nb++)
        acc[mt][nb] = __builtin_amdgcn_mfma_f32_16x16x32_bf16(af[mt], bfr[nb], acc[mt][nb], 0, 0, 0);
    __syncthreads();
  }

#pragma unroll
  for (int nb = 0; nb < 4; nb++) {
    const int col = col0 + wn * 64 + nb * 16 + l16;
    const int mat = col >> 10;
    const int cn  = col & 1023;
    const float* bias = (mat == 0) ? bq : (mat == 1) ? bk : bv;
    const float bb = bias[cn];
    const float qs = (mat == 0) ? 0.03125f : 1.0f;  // fold 1/sqrt(C) into Q
#pragma unroll
    for (int mt = 0; mt < 4; mt++) {
#pragma unroll
      for (int r = 0; r < 4; r++) {
        const int row = row0 + wm * 64 + mt * 16 + quad * 4 + r;
        short o = f2bf((acc[mt][nb][r] + bb) * qs);
        const int bat = row >> 11, t = row & 2047;
        if (mat <= 1) {
          const size_t idx = ((((size_t)bat * 128 + (t >> 4)) * 32 + (cn >> 5)) << 9)
                           + ((((cn >> 3) & 3) * 16 + (t & 15)) << 3) + (cn & 7);
          if (mat == 0) Qf[idx] = o; else Kf[idx] = o;
        } else {
          const size_t idx = ((((size_t)bat * 64 + (cn >> 4)) * 64 + (t >> 5)) << 9)
                           + ((((t >> 3) & 3) * 16 + (cn & 15)) << 3) + (t & 7);
          Vf[idx] = o;
        }
      }
    }
  }
}

// ---------------- Kernel 2: flash attention, causal. Block = 512 thr (8 waves).
// Q-tile = 32 rows, KV-tile = 64.
// QK^T: wave (mh = w>>2, dgrp = w&3) computes 16 q-rows x 64 kv over d in [dgrp*256,..+256);
//       Q frags register-resident (loaded once); partials summed via LDS in softmax.
// PV  : wave w owns 128 V cols, both 16-row halves: O = 2x8 floatx4 = 64 VGPR.
// All global loads are coalesced fragment-linear (lane*8). 2 barriers / k-tile.
__global__ __launch_bounds__(512, 4) void flash_attn(
    const short* __restrict__ Qf, const short* __restrict__ Kf,
    const short* __restrict__ Vf, float* __restrict__ out) {
  __shared__ float Sf[4][32][65];
  __shared__ short Pb[32][72];
  __shared__ float arow[32];
  __shared__ float lrow[32];

  const int b  = blockIdx.x & 7;
  const int idx = blockIdx.x >> 3;                     // 0..63
  const int qt = (idx < 32) ? (63 - idx) : (idx - 32); // pair heavy+light per CU
  const int tid = threadIdx.x;
  const int wave = tid >> 6, lane = tid & 63;
  const int quad = lane >> 4, l16 = lane & 15;
  const int dgrp = wave & 3, mh = wave >> 2;

  // Q fragments: 16 rows (mh half) x 256 d's (dgrp quarter), loaded once, coalesced
  const short* qp = Qf + ((((size_t)b * 128 + qt * 2 + mh) * 32 + dgrp * 8) << 9) + lane * 8;
  bf16x8 qfr[8];
#pragma unroll
  for (int dc = 0; dc < 8; dc++)
    qfr[dc] = *(const bf16x8*)(qp + (dc << 9));

  const int row = tid >> 4, sub = tid & 15;  // softmax: row's 16 threads in ONE wave
  const int gr = qt * 32 + row;
  const int ntiles = (qt >> 1) + 1;

  floatx4 O[2][8] = {};
  float m_i = -1e30f, l_i = 0.0f;

  for (int kt = 0; kt < ntiles; kt++) {
    // ---- partial S over this wave's 256 d's, 64 kv cols (4 indep chains)
    const short* kp = Kf + ((((size_t)b * 128 + kt * 4) * 32 + dgrp * 8) << 9) + lane * 8;
    floatx4 s[4] = {};
#pragma unroll
    for (int nt = 0; nt < 4; nt++)
#pragma unroll
      for (int dc = 0; dc < 8; dc++) {
        bf16x8 kb = *(const bf16x8*)(kp + ((nt * 32 + dc) << 9));
        s[nt] = __builtin_amdgcn_mfma_f32_16x16x32_bf16(qfr[dc], kb, s[nt], 0, 0, 0);
      }
#pragma unroll
    for (int nt = 0; nt < 4; nt++)
#pragma unroll
      for (int r = 0; r < 4; r++)
        Sf[dgrp][mh * 16 + quad * 4 + r][nt * 16 + l16] = s[nt][r];
    __syncthreads();  // B0: all partials in LDS

    // ---- online softmax (sum 4 partials, register m/l, shuffle reduce 16 lanes)
    const int kvbase = kt * 64;
    float sv[4], mx = -1e30f;
#pragma unroll
    for (int j = 0; j < 4; j++) {
      const int c = sub * 4 + j;
      float v = Sf[0][row][c] + Sf[1][row][c] + Sf[2][row][c] + Sf[3][row][c];
      if (kvbase + c > gr) v = -1e30f;  // causal mask
      sv[j] = v;
      mx = fmaxf(mx, v);
    }
#pragma unroll
    for (int msk = 1; msk <= 8; msk <<= 1)
      mx = fmaxf(mx, __shfl_xor(mx, msk, 64));
    const float mn = fmaxf(m_i, mx);
    const float alpha = __expf(m_i - mn);
    m_i = mn;
    float ps = 0.0f;
#pragma unroll
    for (int j = 0; j < 4; j++) {
      float p = __expf(sv[j] - mn);
      ps += p;
      Pb[row][sub * 4 + j] = f2bf(p);
    }
#pragma unroll
    for (int msk = 1; msk <= 8; msk <<= 1)
      ps += __shfl_xor(ps, msk, 64);
    l_i = l_i * alpha + ps;
    if (sub == 0) arow[row] = alpha;
    __syncthreads();  // B1: Pb + arow ready

    // ---- O = diag(alpha) O + P V   (wave owns 128 V cols, both row-halves)
    float al[2][4];
#pragma unroll
    for (int m = 0; m < 2; m++)
#pragma unroll
      for (int r = 0; r < 4; r++) al[m][r] = arow[m * 16 + quad * 4 + r];
#pragma unroll
    for (int m = 0; m < 2; m++)
#pragma unroll
      for (int nb = 0; nb < 8; nb++)
#pragma unroll
        for (int r = 0; r < 4; r++) O[m][nb][r] *= al[m][r];

    const short* vp = Vf + ((((size_t)b * 64 + wave * 8) * 64 + kt * 2) << 9) + lane * 8;
#pragma unroll
    for (int kc = 0; kc < 2; kc++) {
      bf16x8 pa0 = *(const bf16x8*)&Pb[l16][kc * 32 + quad * 8];
      bf16x8 pa1 = *(const bf16x8*)&Pb[16 + l16][kc * 32 + quad * 8];
#pragma unroll
      for (int nb = 0; nb < 8; nb++) {
        bf16x8 vb = *(const bf16x8*)(vp + ((nb * 64 + kc) << 9));
        O[0][nb] = __builtin_amdgcn_mfma_f32_16x16x32_bf16(pa0, vb, O[0][nb], 0, 0, 0);
        O[1][nb] = __builtin_amdgcn_mfma_f32_16x16x32_bf16(pa1, vb, O[1][nb], 0, 0, 0);
      }
    }
  }

  if (sub == 0) lrow[row] = 1.0f / l_i;
  __syncthreads();
  float li[2][4];
#pragma unroll
  for (int m = 0; m < 2; m++)
#pragma unroll
    for (int r = 0; r < 4; r++) li[m][r] = lrow[m * 16 + quad * 4 + r];
#pragma unroll
  for (int m = 0; m < 2; m++)
#pragma unroll
    for (int nb = 0; nb < 8; nb++)
#pragma unroll
      for (int r = 0; r < 4; r++) {
        const int rr = qt * 32 + m * 16 + quad * 4 + r;
        const int cc = wave * 128 + nb * 16 + l16;
        out[((size_t)b * 2048 + rr) * 1024 + cc] = O[m][nb][r] * li[m][r];
      }
}

extern "C" void kernel_launch(void* const* d_in, const int* in_sizes, int n_in,
                              void* d_out, int out_size, void* d_ws, size_t ws_size,
                              hipStream_t stream) {
  const float* x  = (const float*)d_in[0];
  const float* Wq = (const float*)d_in[1];
  const float* bq = (const float*)d_in[2];
  const float* Wk = (const float*)d_in[3];
  const float* bk = (const float*)d_in[4];
  const float* Wv = (const float*)d_in[5];
  const float* bv = (const float*)d_in[6];
  float* out = (float*)d_out;

  char* ws = (char*)d_ws;
  short* Xb = (short*)(ws);                 // 16384x1024 bf16 = 33,554,432 B
  short* Wb = (short*)(ws + 33554432);      // 3x1024x1024 bf16 = 6,291,456 B
  short* Qf = (short*)(ws + 39845888);      // 33,554,432 B fragment-linear (pre-scaled 1/32)
  short* Kf = (short*)(ws + 73400320);      // 33,554,432 B fragment-linear
  short* Vf = (short*)(ws + 106954752);     // 33,554,432 B fragment-linear

  cvt_kernel<<<19456, 256, 0, stream>>>(x, Wq, Wk, Wv, Xb, Wb);
  qkv_gemm<<<dim3(128, 24), 256, 0, stream>>>(Xb, Wb, bq, bk, bv, Qf, Kf, Vf);
  // 8 batches x 64 q-tiles of 32 rows; heavy/light paired for per-CU balance
  flash_attn<<<512, 512, 0, stream>>>(Qf, Kf, Vf, out);
}